// Round 3
// baseline (420.469 us; speedup 1.0000x reference)
//
#include <hip/hip_runtime.h>

typedef unsigned short u16;
typedef short short8 __attribute__((ext_vector_type(8)));
typedef float f32x4 __attribute__((ext_vector_type(4)));

// ---------- helpers ----------
__device__ __forceinline__ u16 f2b(float x){
  union{float f; unsigned u;} v; v.f = x;
  unsigned r = (v.u + 0x7FFFu + ((v.u >> 16) & 1u)) >> 16;
  return (u16)r;
}
__device__ __forceinline__ float b2f(u16 h){
  union{unsigned u; float f;} v; v.u = ((unsigned)h) << 16; return v.f;
}
__device__ __forceinline__ float sigm(float x){ return 1.0f/(1.0f + __expf(-x)); }
__device__ __forceinline__ float tanh_f(float x){ return 1.0f - 2.0f/(1.0f + __expf(2.0f*x)); }

// ---------- prep: xe gather->bf16, Wcomb, bias, Whh MFMA-fragment hi/lo repack, W1 repack, hbt pad ----------
__global__ void prep_kernel(const int* __restrict__ x, const float* __restrict__ emb,
   const float* __restrict__ Wih_f, const float* __restrict__ Whh_f,
   const float* __restrict__ bih_f, const float* __restrict__ bhh_f,
   const float* __restrict__ Wih_b, const float* __restrict__ Whh_b,
   const float* __restrict__ bih_b, const float* __restrict__ bhh_b,
   const float* __restrict__ W1,
   u16* __restrict__ xe, u16* __restrict__ wc, float* __restrict__ biasC,
   u16* __restrict__ whhF, u16* __restrict__ w1b, u16* __restrict__ hbt)
{
  int id = blockIdx.x*256 + threadIdx.x;
  const int N0 = 32768*128;   // xe  [p][k]
  const int N1 = 832*128;     // wc  [n][k]
  const int N2 = 800;         // biasC
  const int N3 = 229376;      // whhF [dir][tau(28)][kc(4)][s(2)][lane(64)][e(8)] bf16
  const int N4 = 672*320;     // w1b  (id = k*320+n)
  const int N5 = 32768*24;    // hbt pad cols 200..223
  if (id < N0){
    int p = id >> 7, k = id & 127;
    float v = 0.f;
    if (k < 100) v = emb[x[p]*100 + k];
    xe[id] = f2b(v);
    return;
  }
  id -= N0;
  if (id < N1){
    int n = id >> 7, k = id & 127;
    float v = 0.f;
    if (k < 100){
      if (n < 400) v = Wih_f[n*100+k];
      else if (n < 800) v = Wih_b[(n-400)*100+k];
    }
    wc[id] = f2b(v);
    return;
  }
  id -= N1;
  if (id < N2){
    biasC[id] = (id < 400) ? (bih_f[id]+bhh_f[id]) : (bih_b[id-400]+bhh_b[id-400]);
    return;
  }
  id -= N2;
  if (id < N3){
    // layout: id = dir*114688 + tau*4096 + kc*1024 + s*512 + l*8 + e
    int dir = id / 114688; int r = id - dir*114688;
    int tau = r >> 12;
    int r2 = r & 4095;
    int kc = r2 >> 10; int r3 = r2 & 1023;
    int s  = r3 >> 9;  int r4 = r3 & 511;
    int l  = r4 >> 3;  int e  = r4 & 7;
    int g  = tau / 7;
    int j  = (tau - g*7)*16 + (l & 15);
    int kk = kc*32 + (l >> 4)*8 + e;
    float v = 0.f;
    if (j < 100 && kk < 100){
      const float* W = dir ? Whh_b : Whh_f;
      v = W[(g*100 + j)*100 + kk];
    }
    u16 hi = f2b(v);
    u16 outv = hi;
    if (s){ float lor = v - b2f(hi); outv = f2b(lor); }
    whhF[id] = outv;
    return;
  }
  id -= N3;
  if (id < N4){
    int k = id / 320; int n = id - k*320;
    int seg = k / 224; int wwk = k - seg*224;
    float v = 0.f;
    if (n < 300 && wwk < 200) v = W1[(seg*200 + wwk)*300 + n];
    w1b[n*672 + k] = f2b(v);
    return;
  }
  id -= N4;
  if (id < N5){
    int p = id / 24; int k = id - p*24;
    hbt[p*224 + 200 + k] = 0;
  }
}

// ---------- GEMM1: inp[d][b][t][j] = xe @ Wcomb^T + bias, bf16 MFMA ----------
__global__ __launch_bounds__(256) void gemm1_kernel(const u16* __restrict__ xe,
    const u16* __restrict__ wc, const float* __restrict__ biasC, u16* __restrict__ inp)
{
  __shared__ __align__(16) u16 As[64*136];
  __shared__ __align__(16) u16 Bs[64*136];
  const int m0 = blockIdx.x*64, n0 = blockIdx.y*64;
  const int tid = threadIdx.x;
  #pragma unroll
  for (int i=0;i<4;i++){
    int f = i*256 + tid;
    int row = f >> 4, c8 = f & 15;
    *(uint4*)&As[row*136 + c8*8] = *(const uint4*)&xe[(m0+row)*128 + c8*8];
    *(uint4*)&Bs[row*136 + c8*8] = *(const uint4*)&wc[(n0+row)*128 + c8*8];
  }
  __syncthreads();
  const int w = tid >> 6, lane = tid & 63, col = lane & 15, quad = lane >> 4;
  f32x4 acc[4];
  #pragma unroll
  for (int nt=0;nt<4;nt++) acc[nt] = (f32x4){0.f,0.f,0.f,0.f};
  #pragma unroll
  for (int kc=0;kc<4;kc++){
    short8 af = *(const short8*)&As[(w*16+col)*136 + kc*32 + quad*8];
    #pragma unroll
    for (int nt=0;nt<4;nt++){
      short8 bfrag = *(const short8*)&Bs[(nt*16+col)*136 + kc*32 + quad*8];
      acc[nt] = __builtin_amdgcn_mfma_f32_16x16x32_bf16(af, bfrag, acc[nt], 0, 0, 0);
    }
  }
  #pragma unroll
  for (int nt=0;nt<4;nt++){
    int n = n0 + nt*16 + col;
    if (n < 800){
      float bs = biasC[n];
      int dir = (n >= 400) ? 1 : 0;
      int j = n - dir*400;
      #pragma unroll
      for (int r=0;r<4;r++){
        int m = m0 + w*16 + quad*4 + r;
        inp[(dir*32768 + m)*400 + j] = f2b(acc[nt][r] + bs);
      }
    }
  }
}

// ---------- LSTM recurrence via MFMA: 64 blocks x 8 chains, gates = h @ WhhT in 16x16x32 bf16 ----------
// hi/lo split of both h and Whh (3 passes) keeps the recurrence at ~fp32 precision.
// Wave w (0..6) owns gate columns j in [16w,16w+16) for all 4 gate types (tiles 7g+w);
// wave 7 is the inp staging producer. One barrier per step (h parity double-buffer).
__global__ __launch_bounds__(512, 2) void lstm_kernel(const u16* __restrict__ inp,
    const u16* __restrict__ whhF, u16* __restrict__ hbt)
{
  __shared__ __align__(16) u16 hhk[2][2][16][16][8];  // [par][hi/lo][k-slot][chain][pos]
  __shared__ __align__(16) u16 inp_s[2][8][400];      // [buf][chain][g*100+j]
  const int beta = blockIdx.x;
  const int dir = beta >> 5, b0 = (beta & 31) * 8;
  const int tid = threadIdx.x;
  const int w = tid >> 6, lane = tid & 63, col = lane & 15, q = lane >> 4;

  // zero h buffers (covers pad rows 8-15 and k>=100 forever)
  for (int i = tid; i < 1024; i += 512) ((uint4*)hhk)[i] = make_uint4(0u,0u,0u,0u);

  // B-fragments (Whh hi/lo), static across steps; AGPR-resident is fine (MFMA reads AGPR)
  short8 wf[4][4][2];
  f32x4 acc[4];
  float cst[2]; cst[0] = 0.f; cst[1] = 0.f;
  if (w < 7){
    const u16* wp = whhF + (size_t)dir*114688;
    #pragma unroll
    for (int gi=0; gi<4; gi++)
      #pragma unroll
      for (int kc=0; kc<4; kc++)
        #pragma unroll
        for (int s=0; s<2; s++)
          wf[gi][kc][s] = *(const short8*)&wp[(7*gi + w)*4096 + kc*1024 + s*512 + lane*8];
  }
  // prologue: stage t(0) into buf 0
  if (w == 7){
    const int t0 = dir ? 127 : 0;
    #pragma unroll
    for (int i=0;i<7;i++){
      int v = i*64 + lane;
      if (v < 400){
        int ch = v/50, off = v - ch*50;
        const u16* gp = inp + ((size_t)(dir*32768 + (b0+ch)*128 + t0))*400 + off*8;
        *(uint4*)&inp_s[0][ch][off*8] = *(const uint4*)gp;
      }
    }
  }
  __syncthreads();

  const int jl = 16*w + col;                 // this lane's gate-local j
  const bool jv = (w < 7) && (jl < 100);
  const int qq = q & 1;

  for (int step=0; step<128; step++){
    const int t = dir ? 127-step : step;
    const int par = step & 1;
    // ---- MFMA phase (waves 0-6): gates_pre = h @ WhhT (hi/lo 3-pass) ----
    if (w < 7){
      short8 ah[4], al[4];
      #pragma unroll
      for (int kc=0; kc<4; kc++){
        ah[kc] = *(const short8*)&hhk[par][0][kc*4+q][col][0];
        al[kc] = *(const short8*)&hhk[par][1][kc*4+q][col][0];
      }
      #pragma unroll
      for (int gi=0; gi<4; gi++){
        f32x4 a = (f32x4){0.f,0.f,0.f,0.f};
        #pragma unroll
        for (int kc=0; kc<4; kc++){
          a = __builtin_amdgcn_mfma_f32_16x16x32_bf16(ah[kc], wf[gi][kc][0], a, 0, 0, 0);
          a = __builtin_amdgcn_mfma_f32_16x16x32_bf16(al[kc], wf[gi][kc][0], a, 0, 0, 0);
          a = __builtin_amdgcn_mfma_f32_16x16x32_bf16(ah[kc], wf[gi][kc][1], a, 0, 0, 0);
        }
        acc[gi] = a;
      }
    }
    // ---- staging next inp tile (wave 7, producer) ----
    if (w == 7 && step < 127){
      int tn = dir ? 127-(step+1) : step+1;
      #pragma unroll
      for (int i=0;i<7;i++){
        int v = i*64 + lane;
        if (v < 400){
          int ch = v/50, off = v - ch*50;
          const u16* gp = inp + ((size_t)(dir*32768 + (b0+ch)*128 + tn))*400 + off*8;
          *(uint4*)&inp_s[(step+1)&1][ch][off*8] = *(const uint4*)gp;
        }
      }
    }
    // ---- activation + cell update (in-register, spread over all 4 quads) ----
    if (w < 7){
      #pragma unroll
      for (int u=0; u<2; u++){
        // lanes q<2 keep rows r=u; lanes q>=2 take rows r=2+u from lane-32
        float p0 = __shfl(acc[0][2+u], (lane+32)&63);
        float p1 = __shfl(acc[1][2+u], (lane+32)&63);
        float p2 = __shfl(acc[2][2+u], (lane+32)&63);
        float p3 = __shfl(acc[3][2+u], (lane+32)&63);
        float gI = (q < 2) ? acc[0][u] : p0;
        float gF = (q < 2) ? acc[1][u] : p1;
        float gG = (q < 2) ? acc[2][u] : p2;
        float gO = (q < 2) ? acc[3][u] : p3;
        if (jv){
          int rr = (q >> 1)*2 + u;
          int ch = qq*4 + rr;
          const u16* ip = &inp_s[par][ch][0];
          gI += b2f(ip[jl]);
          gF += b2f(ip[100+jl]);
          gG += b2f(ip[200+jl]);
          gO += b2f(ip[300+jl]);
          float cc = sigm(gF)*cst[u] + sigm(gI)*tanh_f(gG);
          cst[u] = cc;
          float h = sigm(gO)*tanh_f(cc);
          u16 hi = f2b(h);
          float lor = h - b2f(hi);
          u16 lo = f2b(lor);
          hhk[par^1][0][jl>>3][ch][jl&7] = hi;
          hhk[par^1][1][jl>>3][ch][jl&7] = lo;
          hbt[((size_t)(b0+ch)*128 + t)*224 + dir*100 + jl] = hi;
        }
      }
    }
    __syncthreads();
  }
}

// ---------- MLP: gathered bf16 MFMA GEMM + tanh + W2 + softmax fused ----------
__global__ __launch_bounds__(512) void mlp_kernel(const u16* __restrict__ hbt,
    const u16* __restrict__ w1b, const int* __restrict__ paths,
    const float* __restrict__ b1, const float* __restrict__ W2,
    const float* __restrict__ b2, float* __restrict__ out)
{
  __shared__ __align__(16) u16 As[128*40];
  __shared__ __align__(16) u16 Bs[320*40];
  const int m0 = blockIdx.x*128;
  const int tid = threadIdx.x;
  const int arow = tid >> 2, ac8 = tid & 3;
  const int am = m0 + arow;
  const int ab = am / 255;
  const int w = tid >> 6, lane = tid & 63, col = lane & 15, quad = lane >> 4;
  f32x4 acc[20];
  #pragma unroll
  for (int nt=0;nt<20;nt++) acc[nt] = (f32x4){0.f,0.f,0.f,0.f};
  for (int kc=0;kc<21;kc++){
    __syncthreads();
    for (int f = tid; f < 1280; f += 512){
      int br = f >> 2, bc = f & 3;
      *(uint4*)&Bs[br*40 + bc*8] = *(const uint4*)&w1b[br*672 + kc*32 + bc*8];
    }
    int seg = (kc >= 14) ? 2 : (kc >= 7 ? 1 : 0);
    int ko = kc - seg*7;
    int it = paths[am*3 + seg];
    uint4 v = make_uint4(0u,0u,0u,0u);
    if (it >= 0){
      int t = it > 127 ? 127 : it;
      v = *(const uint4*)&hbt[(ab*128 + t)*224 + ko*32 + ac8*8];
    }
    *(uint4*)&As[arow*40 + ac8*8] = v;
    __syncthreads();
    short8 af = *(const short8*)&As[(w*16+col)*40 + quad*8];
    #pragma unroll
    for (int nt=0;nt<20;nt++){
      short8 bfrag = *(const short8*)&Bs[(nt*16+col)*40 + quad*8];
      acc[nt] = __builtin_amdgcn_mfma_f32_16x16x32_bf16(af, bfrag, acc[nt], 0, 0, 0);
    }
  }
  float pz[4][3];
  #pragma unroll
  for (int r=0;r<4;r++){ pz[r][0]=0.f; pz[r][1]=0.f; pz[r][2]=0.f; }
  #pragma unroll
  for (int nt=0;nt<20;nt++){
    int n = nt*16 + col;
    if (n < 300){
      float bb = b1[n];
      float w20 = W2[n*3+0], w21 = W2[n*3+1], w22 = W2[n*3+2];
      #pragma unroll
      for (int r=0;r<4;r++){
        float hdn = tanh_f(acc[nt][r] + bb);
        pz[r][0] = fmaf(hdn, w20, pz[r][0]);
        pz[r][1] = fmaf(hdn, w21, pz[r][1]);
        pz[r][2] = fmaf(hdn, w22, pz[r][2]);
      }
    }
  }
  #pragma unroll
  for (int off=1; off<16; off<<=1){
    #pragma unroll
    for (int r=0;r<4;r++){
      pz[r][0] += __shfl_xor(pz[r][0], off, 64);
      pz[r][1] += __shfl_xor(pz[r][1], off, 64);
      pz[r][2] += __shfl_xor(pz[r][2], off, 64);
    }
  }
  float c0 = b2[0], c1 = b2[1], c2 = b2[2];
  #pragma unroll
  for (int r=0;r<4;r++){
    float z0 = pz[r][0]+c0, z1 = pz[r][1]+c1, z2 = pz[r][2]+c2;
    float mx = fmaxf(z0, fmaxf(z1, z2));
    float e0 = __expf(z0-mx), e1 = __expf(z1-mx), e2 = __expf(z2-mx);
    float inv = 1.0f/(e0+e1+e2);
    if (col < 3){
      float pv = (col==0 ? e0 : (col==1 ? e1 : e2)) * inv;
      out[(m0 + w*16 + quad*4 + r)*3 + col] = pv;
    }
  }
}

// ---------- launch ----------
extern "C" void kernel_launch(void* const* d_in, const int* in_sizes, int n_in,
                              void* d_out, int out_size, void* d_ws, size_t ws_size,
                              hipStream_t stream)
{
  const int*   x     = (const int*)  d_in[0];
  const int*   paths = (const int*)  d_in[1];
  const float* emb   = (const float*)d_in[2];
  const float* Wih_f = (const float*)d_in[3];
  const float* Whh_f = (const float*)d_in[4];
  const float* bih_f = (const float*)d_in[5];
  const float* bhh_f = (const float*)d_in[6];
  const float* Wih_b = (const float*)d_in[7];
  const float* Whh_b = (const float*)d_in[8];
  const float* bih_b = (const float*)d_in[9];
  const float* bhh_b = (const float*)d_in[10];
  const float* W1    = (const float*)d_in[11];
  const float* b1    = (const float*)d_in[12];
  const float* W2    = (const float*)d_in[13];
  const float* b2    = (const float*)d_in[14];
  float* out = (float*)d_out;

  char* ws = (char*)d_ws;
  u16*   xe    = (u16*)  (ws + 0);          //  8,388,608 B
  u16*   wc    = (u16*)  (ws + 8388608);    //    212,992 B
  float* biasC = (float*)(ws + 8601600);    //      3,200 B
  u16*   whhF  = (u16*)  (ws + 8604800);    //    458,752 B
  u16*   w1b   = (u16*)  (ws + 9063552);    //    430,080 B
  u16*   inp   = (u16*)  (ws + 9493632);    // 52,428,800 B
  u16*   hbt   = (u16*)  (ws + 61922432);   // 14,680,064 B  (total 76,602,496)

  const int prep_total = 32768*128 + 832*128 + 800 + 229376 + 672*320 + 32768*24;
  prep_kernel<<<(prep_total + 255)/256, 256, 0, stream>>>(
      x, emb, Wih_f, Whh_f, bih_f, bhh_f, Wih_b, Whh_b, bih_b, bhh_b, W1,
      xe, wc, biasC, whhF, w1b, hbt);
  gemm1_kernel<<<dim3(512, 13), 256, 0, stream>>>(xe, wc, biasC, inp);
  lstm_kernel<<<64, 512, 0, stream>>>(inp, whhF, hbt);
  mlp_kernel<<<510, 512, 0, stream>>>(hbt, w1b, paths, b1, W2, b2, out);
}